// Round 5
// baseline (191.946 us; speedup 1.0000x reference)
//
#include <hip/hip_runtime.h>
#include <stdint.h>
#include <math.h>

// Problem constants
#define B_    2
#define T_    2048
#define C_    1024
#define H_    16
#define D_    64
#define MTOT  4096            // B*T
#define NQKV  3072            // 3*C
#define KDIM  1024            // C

#define LOG2E 1.4426950408889634f

typedef short short8 __attribute__((ext_vector_type(8)));   // 8 bf16 in 4 VGPRs
typedef float f32x4  __attribute__((ext_vector_type(4)));

__device__ __forceinline__ uint16_t f2b(float f) {
    union { float f; uint32_t u; } x; x.f = f;
    uint32_t u = x.u;
    return (uint16_t)((u + 0x7FFFu + ((u >> 16) & 1u)) >> 16);   // RNE
}
// fast pack of two floats -> two bf16 in one u32 (round-to-nearest, no tie-even)
__device__ __forceinline__ uint32_t packb2(float a, float b) {
    union { float f; uint32_t u; } x, y; x.f = a; y.f = b;
    return ((x.u + 0x8000u) >> 16) | ((y.u + 0x8000u) & 0xffff0000u);
}
__device__ __forceinline__ uint32_t packb2_rne(float a, float b) {
    return (uint32_t)f2b(a) | ((uint32_t)f2b(b) << 16);
}
__device__ __forceinline__ float fexp2(float x) {
#if __has_builtin(__builtin_amdgcn_exp2f)
    return __builtin_amdgcn_exp2f(x);
#else
    return exp2f(x);
#endif
}

// async global->LDS, 16B per lane. LDS dest is wave-uniform base + lane*16 (m104);
// per-lane GLOBAL address carries the XOR swizzle (m173 pre-swizzled-source pattern).
__device__ __forceinline__ void gload16(const uint16_t* g, uint16_t* l) {
    __builtin_amdgcn_global_load_lds((const __attribute__((address_space(1))) uint32_t*)g,
                                     (__attribute__((address_space(3))) uint32_t*)l,
                                     16, 0, 0);
}

// ---------------------------------------------------------------- casts (merged)
__global__ __launch_bounds__(256) void cast_all(const float* __restrict__ x,
                                                const float* __restrict__ wa,
                                                uint16_t* __restrict__ xb,
                                                uint16_t* __restrict__ wab,
                                                int n4x, int n4w) {
    int i = blockIdx.x * blockDim.x + threadIdx.x;
    const float* src; uint16_t* dst; int j;
    if (i < n4x) { src = x; dst = xb; j = i; }
    else { j = i - n4x; if (j >= n4w) return; src = wa; dst = wab; }
    float4 v = ((const float4*)src)[j];
    ushort4 o;
    o.x = f2b(v.x); o.y = f2b(v.y); o.z = f2b(v.z); o.w = f2b(v.w);
    ((ushort4*)dst)[j] = o;
}

// Wt[d][j=h*64+v] = Wp_flat[h*65536 + d*64 + v], bf16
__global__ __launch_bounds__(256) void cast_wp(const float* __restrict__ wp,
                                               uint16_t* __restrict__ wt) {
    int i = blockIdx.x * blockDim.x + threadIdx.x;   // over 1024*1024/4
    int j4 = (i & 255) * 4;
    int d  = i >> 8;
    int h = j4 >> 6, v = j4 & 63;
    float4 val = *(const float4*)(wp + h * 65536 + d * 64 + v);
    ushort4 o;
    o.x = f2b(val.x); o.y = f2b(val.y); o.z = f2b(val.z); o.w = f2b(val.w);
    *(ushort4*)(wt + d * 1024 + j4) = o;
}

// ---------------------------------------------------------------- GEMM1 (256x256 tile, 8 waves, BK=64)
// qkv = x @ Wa^T; scatter: Q (scaled by log2e), K -> [B][H][T][D]; V -> [B][H][D][T]
// Structure: per-wave 128x64 output (8x4 16x16 tiles => 512 MFMA/CU per barrier window),
// gload_lds staging with counted vmcnt(8) that never drains in the main loop,
// double-buffered 128KB LDS (1 block/CU), XOR-swizzled via pre-swizzled global source.
__global__ __launch_bounds__(512, 2) void gemm_qkv(const uint16_t* __restrict__ A,   // x bf16 [4096][1024]
                                                   const uint16_t* __restrict__ Bw,  // Wa bf16 [3072][1024]
                                                   uint16_t* __restrict__ qkvb) {
    __shared__ __align__(16) uint16_t As[2][256 * 64];   // (r,k): logical chunk kc at phys slot kc^(r&7)
    __shared__ __align__(16) uint16_t Bs[2][256 * 64];

    int tid = threadIdx.x;
    int w = tid >> 6, lane = tid & 63;
    int qd = lane >> 4, ln = lane & 15;
    int lnx = ln & 7;
    int wm = w >> 2, wn = w & 3;          // 2M x 4N wave grid
    int rowBase = blockIdx.y * 256;
    int colBase = blockIdx.x * 256;

    // staging: lane l covers row (w*8 + l>>3) of each 64-row group, phys slot l&7,
    // logical chunk (l&7)^(l>>3) — so linear LDS dest gets the XOR-swizzled layout.
    int l8 = lane >> 3, l7 = lane & 7;
    int gch = l7 ^ l8;
    const uint16_t* ga = A  + (size_t)(rowBase + w * 8 + l8) * KDIM + gch * 8;
    const uint16_t* gb = Bw + (size_t)(colBase + w * 8 + l8) * KDIM + gch * 8;
    int lofs = (w * 8) * 64;              // wave-uniform LDS element base

#define STG(buf, kk)                                                             \
    {   int k0_ = (kk) * 64;                                                     \
        _Pragma("unroll")                                                        \
        for (int m = 0; m < 4; m++)                                              \
            gload16(ga + k0_ + (size_t)m * 64 * KDIM, &As[buf][lofs + m * 64 * 64]); \
        _Pragma("unroll")                                                        \
        for (int m = 0; m < 4; m++)                                              \
            gload16(gb + k0_ + (size_t)m * 64 * KDIM, &Bs[buf][lofs + m * 64 * 64]); }

    f32x4 acc[8][4] = {};
    STG(0, 0);
    STG(1, 1);
    asm volatile("s_waitcnt vmcnt(8)" ::: "memory");   // tile 0 landed; tile 1 in flight
    __builtin_amdgcn_s_barrier();
    asm volatile("" ::: "memory");

    for (int s = 0; s < 16; s++) {
        int cur = s & 1;
        const uint16_t* Ab = &As[cur][0];
        const uint16_t* Bb = &Bs[cur][0];

        // B fragments once per K-tile (shared by all 4 quadrant phases)
        short8 b[4][2];
#pragma unroll
        for (int j = 0; j < 4; j++)
#pragma unroll
            for (int ks = 0; ks < 2; ks++) {
                int p = (ks * 4 + qd) ^ lnx;
                b[j][ks] = *(const short8*)&Bb[(wn * 64 + j * 16 + ln) * 64 + p * 8];
            }
        // 4 quadrant phases: {4 ds_read A-frags, 16 MFMA} each
#pragma unroll
        for (int q = 0; q < 4; q++) {
            short8 a[2][2];
#pragma unroll
            for (int im = 0; im < 2; im++)
#pragma unroll
                for (int ks = 0; ks < 2; ks++) {
                    int p = (ks * 4 + qd) ^ lnx;
                    a[im][ks] = *(const short8*)&Ab[(wm * 128 + (q * 2 + im) * 16 + ln) * 64 + p * 8];
                }
            __builtin_amdgcn_s_setprio(1);
#pragma unroll
            for (int ks = 0; ks < 2; ks++)
#pragma unroll
                for (int im = 0; im < 2; im++)
#pragma unroll
                    for (int j = 0; j < 4; j++)
                        acc[q * 2 + im][j] = __builtin_amdgcn_mfma_f32_16x16x32_bf16(
                            a[im][ks], b[j][ks], acc[q * 2 + im][j], 0, 0, 0);
            __builtin_amdgcn_s_setprio(0);
        }

        asm volatile("" ::: "memory");
        __builtin_amdgcn_s_barrier();          // barrier A: all reads of buf[cur] done
        asm volatile("" ::: "memory");
        if (s + 2 < 16) {
            STG(cur, s + 2);                   // refill freed buffer; 8 issues in flight
            asm volatile("s_waitcnt vmcnt(8)" ::: "memory");   // own tile s+1 landed
        } else if (s + 1 < 16) {
            asm volatile("s_waitcnt vmcnt(0)" ::: "memory");   // last tile: drain
        }
        if (s + 1 < 16) {
            __builtin_amdgcn_s_barrier();      // barrier B: everyone's tile s+1 landed
            asm volatile("" ::: "memory");
        }
    }
#undef STG

    // epilogue: which is block-uniform (colBase 256-aligned within 1024-thirds)
    int which = colBase >> 10;
    float sc = (which == 0) ? LOG2E : 1.0f;    // Q pre-scaled so attn uses exp2
#pragma unroll
    for (int i = 0; i < 8; i++) {
#pragma unroll
        for (int j = 0; j < 4; j++) {
            int gcol = colBase + wn * 64 + j * 16 + ln;
            int rem = gcol & 1023;
            int h = rem >> 6, d = rem & 63;
#pragma unroll
            for (int r = 0; r < 4; r++) {
                int grow = rowBase + wm * 128 + i * 16 + qd * 4 + r;
                int bb = grow >> 11, t = grow & 2047;
                uint16_t val = f2b(acc[i][j][r] * sc);
                if (which == 2) {
                    qkvb[(size_t)2 * 4194304 + (((size_t)(bb * H_ + h) * D_) + d) * T_ + t] = val;   // V^T
                } else {
                    qkvb[(size_t)which * 4194304 + (((size_t)(bb * H_ + h) * T_) + t) * D_ + d] = val;
                }
            }
        }
    }
}

// ---------------------------------------------------------------- attention
// Per-CU-unique-line bound => share K/V tiles across waves via LDS.
// Block = 8 waves (512 thr), handles q-groups j and 15-j (128 q-rows each) in ONE
// fused kt loop (nt = 32-2j staging iterations, 34 strip-iterations — balanced).
// Wave w owns q-rows [qg*128+w*16, +16) exclusively: no split-K, no combine.
// K/V tiles staged once per block per kt (swizzled, reg-prefetch, dbuf, 1 barrier/kt).
// S^T = K Q^T; p = exp2(s) (Q pre-scaled by log2e); P^T via per-wave LDS; O^T = Vt P^T.

#define STRIP(QS, BQ, OT, LSUM)                                              \
    if (kt * 64 <= (QS) + 15) {                                              \
        bool needm = (kt * 64 + 63 > (QS));                                  \
        f32x4 stt[4];                                                        \
        __builtin_amdgcn_s_setprio(1);                                       \
        _Pragma("unroll")                                                    \
        for (int it = 0; it < 4; it++) {                                     \
            f32x4 z = {};                                                    \
            z = __builtin_amdgcn_mfma_f32_16x16x32_bf16(ak[it][0], (BQ)[0], z, 0, 0, 0); \
            z = __builtin_amdgcn_mfma_f32_16x16x32_bf16(ak[it][1], (BQ)[1], z, 0, 0, 0); \
            stt[it] = z;                                                     \
        }                                                                    \
        __builtin_amdgcn_s_setprio(0);                                       \
        if (needm) {                                                         \
            _Pragma("unroll")                                                \
            for (int it = 0; it < 4; it++)                                   \
                _Pragma("unroll")                                            \
                for (int r = 0; r < 4; r++) {                                \
                    int t = kt * 64 + it * 16 + qd * 4 + r;                  \
                    if (t > (QS) + ln) stt[it][r] = -1.0e30f;                \
                }                                                            \
        }                                                                    \
        _Pragma("unroll")                                                    \
        for (int it = 0; it < 4; it++) {                                     \
            float p0 = fexp2(stt[it][0]);                                    \
            float p1 = fexp2(stt[it][1]);                                    \
            float p2 = fexp2(stt[it][2]);                                    \
            float p3 = fexp2(stt[it][3]);                                    \
            (LSUM) += (p0 + p1) + (p2 + p3);                                 \
            uint2 pk2;                                                       \
            pk2.x = packb2(p0, p1);                                          \
            pk2.y = packb2(p2, p3);                                          \
            *(uint2*)&Pl[w][ln][it * 16 + qd * 4] = pk2;                     \
        }                                                                    \
        short8 bp0 = *(const short8*)&Pl[w][ln][qd * 8];                     \
        short8 bp1 = *(const short8*)&Pl[w][ln][32 + qd * 8];                \
        __builtin_amdgcn_s_setprio(1);                                       \
        _Pragma("unroll")                                                    \
        for (int id = 0; id < 4; id++) {                                     \
            (OT)[id] = __builtin_amdgcn_mfma_f32_16x16x32_bf16(av[id][0], bp0, (OT)[id], 0, 0, 0); \
            (OT)[id] = __builtin_amdgcn_mfma_f32_16x16x32_bf16(av[id][1], bp1, (OT)[id], 0, 0, 0); \
        }                                                                    \
        __builtin_amdgcn_s_setprio(0);                                       \
    }

#define EPI(QS, OT, LSUM)                                                    \
    {                                                                        \
        float ssum = (LSUM);                                                 \
        ssum += __shfl_xor(ssum, 16);                                        \
        ssum += __shfl_xor(ssum, 32);                                        \
        float rl = 1.0f / ssum;                                              \
        int q = (QS) + ln;                                                   \
        _Pragma("unroll")                                                    \
        for (int id = 0; id < 4; id++) {                                     \
            float v0 = (OT)[id][0] * rl;                                     \
            float v1 = (OT)[id][1] * rl;                                     \
            float v2 = (OT)[id][2] * rl;                                     \
            float v3 = (OT)[id][3] * rl;                                     \
            uint2 pk2;                                                       \
            pk2.x = packb2_rne(v0, v1);                                      \
            pk2.y = packb2_rne(v2, v3);                                      \
            *(uint2*)&oc[(size_t)(b * T_ + q) * C_ + h * 64 + id * 16 + qd * 4] = pk2; \
        }                                                                    \
    }

__global__ __launch_bounds__(512, 2) void attn(const uint16_t* __restrict__ qkvb,
                                               uint16_t* __restrict__ oc) {         // O_concat bf16 [4096][1024]
    __shared__ __align__(16) uint16_t Ks[2][64 * 64];   // swizzled: (t, chunk c) at t*64 + (c^(t&7))*8
    __shared__ __align__(16) uint16_t Vs[2][64 * 64];   // swizzled: (d, chunk c) likewise
    __shared__ __align__(16) uint16_t Pl[8][16][72];    // per-wave P^T strip [q16][t64+pad]

    int tid = threadIdx.x;
    int w = tid >> 6, lane = tid & 63;
    int qd = lane >> 4, ln = lane & 15;
    int lnx = ln & 7;
    int bid = blockIdx.x;
    int j = bid >> 5;                  // 0..7 pair index
    int bh = bid & 31;                 // bid%8 == bh%8 → bh→XCD L2 affinity
    int b = bh >> 4, h = bh & 15;

    const uint16_t* Q0 = qkvb + (size_t)bh * T_ * D_;
    const uint16_t* K  = Q0 + 4194304;
    const uint16_t* Vt = qkvb + (size_t)2 * 4194304 + (size_t)bh * D_ * T_;   // [64 d][2048 t]

    int qsA = j * 128 + w * 16;        // light q-group
    int qsB = (15 - j) * 128 + w * 16; // heavy q-group
    int nt  = 32 - 2 * j;              // k-tiles needed by the heavy group

    // persistent Q fragments (B-operand, n=q16, k=d)
    short8 bqA[2], bqB[2];
#pragma unroll
    for (int ks = 0; ks < 2; ks++) {
        bqA[ks] = *(const short8*)(Q0 + (size_t)(qsA + ln) * D_ + ks * 32 + qd * 8);
        bqB[ks] = *(const short8*)(Q0 + (size_t)(qsB + ln) * D_ + ks * 32 + qd * 8);
    }

    // staging: 512 threads cover 64 rows x 8 chunks of 16B, chunk XOR-swizzled
    int srow = tid >> 3;               // 0..63
    int pch = tid & 7;
    int gch = pch ^ (srow & 7);
    const uint16_t* gk = K  + (size_t)srow * D_ + gch * 8;   // K row = kt*64+srow
    const uint16_t* gv = Vt + (size_t)srow * T_ + gch * 8;   // V^T row d = srow, col = kt*64+..
    int lofs = srow * 64 + pch * 8;

    short8 pk = *(const short8*)gk;    // tile kt=0 prefetch
    short8 pv = *(const short8*)gv;

    f32x4 otA[4] = {}, otB[4] = {};    // O^T [d-tile id][q16], per strip
    float lA = 0.f, lB = 0.f;

    int c = 0;
    for (int kt = 0; kt < nt; kt++) {
        *(short8*)&Ks[c][lofs] = pk;
        *(short8*)&Vs[c][lofs] = pv;
        __syncthreads();
        if (kt + 1 < nt) {
            pk = *(const short8*)(gk + (size_t)(kt + 1) * 64 * D_);
            pv = *(const short8*)(gv + (size_t)(kt + 1) * 64);
        }
        // shared K/V fragments for both strips (A-operands)
        short8 ak[4][2], av[4][2];
#pragma unroll
        for (int ks = 0; ks < 2; ks++) {
            int p8 = ((ks * 4 + qd) ^ lnx) * 8;
#pragma unroll
            for (int it = 0; it < 4; it++) {
                ak[it][ks] = *(const short8*)&Ks[c][(it * 16 + ln) * 64 + p8];
                av[it][ks] = *(const short8*)&Vs[c][(it * 16 + ln) * 64 + p8];
            }
        }
        STRIP(qsA, bqA, otA, lA);
        STRIP(qsB, bqB, otB, lB);
        c ^= 1;
    }

    EPI(qsA, otA, lA);
    EPI(qsB, otB, lB);
}

// ---------------------------------------------------------------- GEMM2 (tile 128x64, BK=64, swizzled, register prefetch)
__global__ __launch_bounds__(256, 3) void gemm_out(const uint16_t* __restrict__ A,   // O_concat bf16 [4096][1024]
                                                   const uint16_t* __restrict__ Bw,  // Wt bf16 [1024][1024]
                                                   float* __restrict__ out) {        // [4096][1024] fp32
    __shared__ __align__(16) uint16_t As[128 * 64];
    __shared__ __align__(16) uint16_t Bs[64 * 64];

    int tid = threadIdx.x;
    int w = tid >> 6, lane = tid & 63;
    int qd = lane >> 4, ln = lane & 15;
    int lnx = ln & 7;
    int rowBase = blockIdx.y * 128;
    int colBase = blockIdx.x * 64;
    int mw = (w >> 1) * 64, nw = (w & 1) * 32;

    int srow = tid >> 3;
    int pchunk = tid & 7;
    int gchunk = pchunk ^ (srow & 7);

    const uint16_t* ga = A  + (size_t)(rowBase + srow) * KDIM + gchunk * 8;
    const uint16_t* gb = Bw + (size_t)(colBase + srow) * KDIM + gchunk * 8;
    uint16_t* la = &As[srow * 64 + pchunk * 8];
    uint16_t* lb = &Bs[srow * 64 + pchunk * 8];

    short8 pa[4], pb[2];
#pragma unroll
    for (int m = 0; m < 4; m++)
        pa[m] = *(const short8*)(ga + (size_t)m * 32 * KDIM);
#pragma unroll
    for (int m = 0; m < 2; m++)
        pb[m] = *(const short8*)(gb + (size_t)m * 32 * KDIM);

    f32x4 acc[4][2] = {};
    for (int s = 0; s < 16; s++) {
#pragma unroll
        for (int m = 0; m < 4; m++)
            *(short8*)(la + m * 32 * 64) = pa[m];
#pragma unroll
        for (int m = 0; m < 2; m++)
            *(short8*)(lb + m * 32 * 64) = pb[m];
        __syncthreads();
        if (s < 15) {
            int k0 = (s + 1) * 64;
#pragma unroll
            for (int m = 0; m < 4; m++)
                pa[m] = *(const short8*)(ga + k0 + (size_t)m * 32 * KDIM);
#pragma unroll
            for (int m = 0; m < 2; m++)
                pb[m] = *(const short8*)(gb + k0 + (size_t)m * 32 * KDIM);
        }
#pragma unroll
        for (int ks = 0; ks < 2; ks++) {
            int p = (ks * 4 + qd) ^ lnx;
            short8 a[4], b[2];
#pragma unroll
            for (int i = 0; i < 4; i++)
                a[i] = *(const short8*)&As[(mw + i * 16 + ln) * 64 + p * 8];
#pragma unroll
            for (int j = 0; j < 2; j++)
                b[j] = *(const short8*)&Bs[(nw + j * 16 + ln) * 64 + p * 8];
#pragma unroll
            for (int i = 0; i < 4; i++)
#pragma unroll
                for (int j = 0; j < 2; j++)
                    acc[i][j] = __builtin_amdgcn_mfma_f32_16x16x32_bf16(a[i], b[j], acc[i][j], 0, 0, 0);
        }
        __syncthreads();
    }

#pragma unroll
    for (int i = 0; i < 4; i++)
#pragma unroll
        for (int j = 0; j < 2; j++)
#pragma unroll
            for (int r = 0; r < 4; r++) {
                int grow = rowBase + mw + i * 16 + qd * 4 + r;
                int gcol = colBase + nw + j * 16 + ln;
                out[(size_t)grow * 1024 + gcol] = acc[i][j][r];
            }
}

// ---------------------------------------------------------------- launch
extern "C" void kernel_launch(void* const* d_in, const int* in_sizes, int n_in,
                              void* d_out, int out_size, void* d_ws, size_t ws_size,
                              hipStream_t stream) {
    const float* x  = (const float*)d_in[0];
    const float* Wa = (const float*)d_in[1];
    const float* Wp = (const float*)d_in[2];
    float* out = (float*)d_out;

    uint16_t* ws   = (uint16_t*)d_ws;
    uint16_t* xb   = ws;                       // 4096*1024
    uint16_t* Wab  = xb + 4194304;             // 3072*1024
    uint16_t* Wtb  = Wab + 3145728;            // 1024*1024
    uint16_t* qkvb = Wtb + 1048576;            // Q,K: [bh][t][d] (Q pre-scaled by log2e); V: [bh][d][t]
    uint16_t* ob   = qkvb + (size_t)3 * 4194304; // 4096*1024

    cast_all<<<7168, 256, 0, stream>>>(x, Wa, xb, Wab, 4194304 / 4, 3145728 / 4);
    cast_wp<<<1024, 256, 0, stream>>>(Wp, Wtb);
    gemm_qkv<<<dim3(12, 16), 512, 0, stream>>>(xb, Wab, qkvb);
    attn<<<256, 512, 0, stream>>>(qkvb, ob);
    gemm_out<<<dim3(16, 32), 256, 0, stream>>>(ob, Wtb, out);
}

// Round 6
// 178.527 us; speedup vs baseline: 1.0752x; 1.0752x over previous
//
#include <hip/hip_runtime.h>
#include <stdint.h>
#include <math.h>

// Problem constants
#define B_    2
#define T_    2048
#define C_    1024
#define H_    16
#define D_    64
#define MTOT  4096            // B*T
#define NQKV  3072            // 3*C
#define KDIM  1024            // C

#define LOG2E 1.4426950408889634f

typedef short short8 __attribute__((ext_vector_type(8)));   // 8 bf16 in 4 VGPRs
typedef float f32x4  __attribute__((ext_vector_type(4)));

__device__ __forceinline__ uint16_t f2b(float f) {
    union { float f; uint32_t u; } x; x.f = f;
    uint32_t u = x.u;
    return (uint16_t)((u + 0x7FFFu + ((u >> 16) & 1u)) >> 16);   // RNE
}
// fast pack of two floats -> two bf16 in one u32 (round-to-nearest, no tie-even)
__device__ __forceinline__ uint32_t packb2(float a, float b) {
    union { float f; uint32_t u; } x, y; x.f = a; y.f = b;
    return ((x.u + 0x8000u) >> 16) | ((y.u + 0x8000u) & 0xffff0000u);
}
__device__ __forceinline__ uint32_t packb2_rne(float a, float b) {
    return (uint32_t)f2b(a) | ((uint32_t)f2b(b) << 16);
}
// pack 8 fp32 (two float4) -> short8 bf16, RNE (same rounding as the old cast kernels)
__device__ __forceinline__ short8 cvt8(float4 a, float4 b) {
    union { short8 s; uint32_t u[4]; } r;
    r.u[0] = packb2_rne(a.x, a.y);
    r.u[1] = packb2_rne(a.z, a.w);
    r.u[2] = packb2_rne(b.x, b.y);
    r.u[3] = packb2_rne(b.z, b.w);
    return r.s;
}
__device__ __forceinline__ float fexp2(float x) {
#if __has_builtin(__builtin_amdgcn_exp2f)
    return __builtin_amdgcn_exp2f(x);
#else
    return exp2f(x);
#endif
}

// ---------------------------------------------------------------- GEMM1 (BK=64, swizzled LDS, register prefetch,
// FUSED fp32->bf16 cast in the staging path — no separate cast kernels)
// qkv = x @ Wa^T; scatter: Q (scaled by log2e), K -> [B][H][T][D]; V -> [B][H][D][T]
__global__ __launch_bounds__(256, 3) void gemm_qkv(const float* __restrict__ A,    // x fp32 [4096][1024]
                                                   const float* __restrict__ Bw,   // Wa fp32 [3072][1024]
                                                   uint16_t* __restrict__ qkvb) {
    __shared__ __align__(16) uint16_t As[128 * 64];   // swizzled: (r,k) at r*64 + ((k/8)^(r&7))*8 + k%8
    __shared__ __align__(16) uint16_t Bs[128 * 64];

    int tid = threadIdx.x;
    int w = tid >> 6, lane = tid & 63;
    int qd = lane >> 4, ln = lane & 15;
    int lnx = ln & 7;
    int rowBase = blockIdx.y * 128;
    int colBase = blockIdx.x * 128;
    int mw = (w >> 1) * 64, nw = (w & 1) * 64;

    int srow = tid >> 3;                 // 0..31
    int pchunk = tid & 7;                // physical chunk
    int gchunk = pchunk ^ (srow & 7);    // logical k-chunk for that slot

    const float* ga = A  + (size_t)(rowBase + srow) * KDIM + gchunk * 8;
    const float* gb = Bw + (size_t)(colBase + srow) * KDIM + gchunk * 8;
    uint16_t* la = &As[srow * 64 + pchunk * 8];
    uint16_t* lb = &Bs[srow * 64 + pchunk * 8];

    float4 pa[4][2], pb[4][2];
#pragma unroll
    for (int m = 0; m < 4; m++) {
        pa[m][0] = *(const float4*)(ga + (size_t)m * 32 * KDIM);
        pa[m][1] = *(const float4*)(ga + (size_t)m * 32 * KDIM + 4);
        pb[m][0] = *(const float4*)(gb + (size_t)m * 32 * KDIM);
        pb[m][1] = *(const float4*)(gb + (size_t)m * 32 * KDIM + 4);
    }

    f32x4 acc[4][4] = {};
    for (int s = 0; s < 16; s++) {
        // stage prefetched tile into LDS (convert fp32 -> bf16 here)
#pragma unroll
        for (int m = 0; m < 4; m++) {
            *(short8*)(la + m * 32 * 64) = cvt8(pa[m][0], pa[m][1]);
            *(short8*)(lb + m * 32 * 64) = cvt8(pb[m][0], pb[m][1]);
        }
        __syncthreads();
        // issue next tile's global loads early — latency overlaps the MFMA phase
        if (s < 15) {
            int k0 = (s + 1) * 64;
#pragma unroll
            for (int m = 0; m < 4; m++) {
                pa[m][0] = *(const float4*)(ga + k0 + (size_t)m * 32 * KDIM);
                pa[m][1] = *(const float4*)(ga + k0 + (size_t)m * 32 * KDIM + 4);
                pb[m][0] = *(const float4*)(gb + k0 + (size_t)m * 32 * KDIM);
                pb[m][1] = *(const float4*)(gb + k0 + (size_t)m * 32 * KDIM + 4);
            }
        }
#pragma unroll
        for (int ks = 0; ks < 2; ks++) {
            int p = (ks * 4 + qd) ^ lnx;
            short8 a[4], b[4];
#pragma unroll
            for (int i = 0; i < 4; i++) {
                a[i] = *(const short8*)&As[(mw + i * 16 + ln) * 64 + p * 8];
                b[i] = *(const short8*)&Bs[(nw + i * 16 + ln) * 64 + p * 8];
            }
#pragma unroll
            for (int i = 0; i < 4; i++)
#pragma unroll
                for (int j = 0; j < 4; j++)
                    acc[i][j] = __builtin_amdgcn_mfma_f32_16x16x32_bf16(a[i], b[j], acc[i][j], 0, 0, 0);
        }
        __syncthreads();
    }

#pragma unroll
    for (int i = 0; i < 4; i++) {
#pragma unroll
        for (int j = 0; j < 4; j++) {
            int gcol = colBase + nw + j * 16 + ln;
            int which = gcol >> 10;
            int rem = gcol & 1023;
            int h = rem >> 6, d = rem & 63;
            float sc = (which == 0) ? LOG2E : 1.0f;   // Q pre-scaled so attn uses exp2
#pragma unroll
            for (int r = 0; r < 4; r++) {
                int grow = rowBase + mw + i * 16 + qd * 4 + r;
                int bb = grow >> 11, t = grow & 2047;
                uint16_t val = f2b(acc[i][j][r] * sc);
                if (which == 2) {
                    qkvb[(size_t)2 * 4194304 + (((size_t)(bb * H_ + h) * D_) + d) * T_ + t] = val;   // V^T
                } else {
                    qkvb[(size_t)which * 4194304 + (((size_t)(bb * H_ + h) * T_) + t) * D_ + d] = val;
                }
            }
        }
    }
}

// ---------------------------------------------------------------- attention
// Per-CU-unique-line bound => share K/V tiles across waves via LDS.
// Block = 8 waves (512 thr), handles q-groups j and 15-j (128 q-rows each) in ONE
// fused kt loop (nt = 32-2j staging iterations, 34 strip-iterations — balanced).
// Wave w owns q-rows [qg*128+w*16, +16) exclusively: no split-K, no combine.
// K/V tiles staged once per block per kt (swizzled, reg-prefetch, dbuf, 1 barrier/kt).
// S^T = K Q^T; p = exp2(s) (Q pre-scaled by log2e); P^T via per-wave LDS; O^T = Vt P^T.

#define STRIP(QS, BQ, OT, LSUM)                                              \
    if (kt * 64 <= (QS) + 15) {                                              \
        bool needm = (kt * 64 + 63 > (QS));                                  \
        f32x4 stt[4];                                                        \
        __builtin_amdgcn_s_setprio(1);                                       \
        _Pragma("unroll")                                                    \
        for (int it = 0; it < 4; it++) {                                     \
            f32x4 z = {};                                                    \
            z = __builtin_amdgcn_mfma_f32_16x16x32_bf16(ak[it][0], (BQ)[0], z, 0, 0, 0); \
            z = __builtin_amdgcn_mfma_f32_16x16x32_bf16(ak[it][1], (BQ)[1], z, 0, 0, 0); \
            stt[it] = z;                                                     \
        }                                                                    \
        __builtin_amdgcn_s_setprio(0);                                       \
        if (needm) {                                                         \
            _Pragma("unroll")                                                \
            for (int it = 0; it < 4; it++)                                   \
                _Pragma("unroll")                                            \
                for (int r = 0; r < 4; r++) {                                \
                    int t = kt * 64 + it * 16 + qd * 4 + r;                  \
                    if (t > (QS) + ln) stt[it][r] = -1.0e30f;                \
                }                                                            \
        }                                                                    \
        _Pragma("unroll")                                                    \
        for (int it = 0; it < 4; it++) {                                     \
            float p0 = fexp2(stt[it][0]);                                    \
            float p1 = fexp2(stt[it][1]);                                    \
            float p2 = fexp2(stt[it][2]);                                    \
            float p3 = fexp2(stt[it][3]);                                    \
            (LSUM) += (p0 + p1) + (p2 + p3);                                 \
            uint2 pk2;                                                       \
            pk2.x = packb2(p0, p1);                                          \
            pk2.y = packb2(p2, p3);                                          \
            *(uint2*)&Pl[w][ln][it * 16 + qd * 4] = pk2;                     \
        }                                                                    \
        short8 bp0 = *(const short8*)&Pl[w][ln][qd * 8];                     \
        short8 bp1 = *(const short8*)&Pl[w][ln][32 + qd * 8];                \
        __builtin_amdgcn_s_setprio(1);                                       \
        _Pragma("unroll")                                                    \
        for (int id = 0; id < 4; id++) {                                     \
            (OT)[id] = __builtin_amdgcn_mfma_f32_16x16x32_bf16(av[id][0], bp0, (OT)[id], 0, 0, 0); \
            (OT)[id] = __builtin_amdgcn_mfma_f32_16x16x32_bf16(av[id][1], bp1, (OT)[id], 0, 0, 0); \
        }                                                                    \
        __builtin_amdgcn_s_setprio(0);                                       \
    }

#define EPI(QS, OT, LSUM)                                                    \
    {                                                                        \
        float ssum = (LSUM);                                                 \
        ssum += __shfl_xor(ssum, 16);                                        \
        ssum += __shfl_xor(ssum, 32);                                        \
        float rl = 1.0f / ssum;                                              \
        int q = (QS) + ln;                                                   \
        _Pragma("unroll")                                                    \
        for (int id = 0; id < 4; id++) {                                     \
            float v0 = (OT)[id][0] * rl;                                     \
            float v1 = (OT)[id][1] * rl;                                     \
            float v2 = (OT)[id][2] * rl;                                     \
            float v3 = (OT)[id][3] * rl;                                     \
            uint2 pk2;                                                       \
            pk2.x = packb2_rne(v0, v1);                                      \
            pk2.y = packb2_rne(v2, v3);                                      \
            *(uint2*)&oc[(size_t)(b * T_ + q) * C_ + h * 64 + id * 16 + qd * 4] = pk2; \
        }                                                                    \
    }

__global__ __launch_bounds__(512, 2) void attn(const uint16_t* __restrict__ qkvb,
                                               uint16_t* __restrict__ oc) {         // O_concat bf16 [4096][1024]
    __shared__ __align__(16) uint16_t Ks[2][64 * 64];   // swizzled: (t, chunk c) at t*64 + (c^(t&7))*8
    __shared__ __align__(16) uint16_t Vs[2][64 * 64];   // swizzled: (d, chunk c) likewise
    __shared__ __align__(16) uint16_t Pl[8][16][72];    // per-wave P^T strip [q16][t64+pad]

    int tid = threadIdx.x;
    int w = tid >> 6, lane = tid & 63;
    int qd = lane >> 4, ln = lane & 15;
    int lnx = ln & 7;
    int bid = blockIdx.x;
    int j = bid >> 5;                  // 0..7 pair index
    int bh = bid & 31;                 // bid%8 == bh%8 → bh→XCD L2 affinity
    int b = bh >> 4, h = bh & 15;

    const uint16_t* Q0 = qkvb + (size_t)bh * T_ * D_;
    const uint16_t* K  = Q0 + 4194304;
    const uint16_t* Vt = qkvb + (size_t)2 * 4194304 + (size_t)bh * D_ * T_;   // [64 d][2048 t]

    int qsA = j * 128 + w * 16;        // light q-group
    int qsB = (15 - j) * 128 + w * 16; // heavy q-group
    int nt  = 32 - 2 * j;              // k-tiles needed by the heavy group

    // persistent Q fragments (B-operand, n=q16, k=d)
    short8 bqA[2], bqB[2];
#pragma unroll
    for (int ks = 0; ks < 2; ks++) {
        bqA[ks] = *(const short8*)(Q0 + (size_t)(qsA + ln) * D_ + ks * 32 + qd * 8);
        bqB[ks] = *(const short8*)(Q0 + (size_t)(qsB + ln) * D_ + ks * 32 + qd * 8);
    }

    // staging: 512 threads cover 64 rows x 8 chunks of 16B, chunk XOR-swizzled
    int srow = tid >> 3;               // 0..63
    int pch = tid & 7;
    int gch = pch ^ (srow & 7);
    const uint16_t* gk = K  + (size_t)srow * D_ + gch * 8;   // K row = kt*64+srow
    const uint16_t* gv = Vt + (size_t)srow * T_ + gch * 8;   // V^T row d = srow, col = kt*64+..
    int lofs = srow * 64 + pch * 8;

    short8 pk = *(const short8*)gk;    // tile kt=0 prefetch
    short8 pv = *(const short8*)gv;

    f32x4 otA[4] = {}, otB[4] = {};    // O^T [d-tile id][q16], per strip
    float lA = 0.f, lB = 0.f;

    int c = 0;
    for (int kt = 0; kt < nt; kt++) {
        *(short8*)&Ks[c][lofs] = pk;
        *(short8*)&Vs[c][lofs] = pv;
        __syncthreads();
        if (kt + 1 < nt) {
            pk = *(const short8*)(gk + (size_t)(kt + 1) * 64 * D_);
            pv = *(const short8*)(gv + (size_t)(kt + 1) * 64);
        }
        // shared K/V fragments for both strips (A-operands)
        short8 ak[4][2], av[4][2];
#pragma unroll
        for (int ks = 0; ks < 2; ks++) {
            int p8 = ((ks * 4 + qd) ^ lnx) * 8;
#pragma unroll
            for (int it = 0; it < 4; it++) {
                ak[it][ks] = *(const short8*)&Ks[c][(it * 16 + ln) * 64 + p8];
                av[it][ks] = *(const short8*)&Vs[c][(it * 16 + ln) * 64 + p8];
            }
        }
        STRIP(qsA, bqA, otA, lA);
        STRIP(qsB, bqB, otB, lB);
        c ^= 1;
    }

    EPI(qsA, otA, lA);
    EPI(qsB, otB, lB);
}

// ---------------------------------------------------------------- GEMM2 (tile 128x64, BK=64, swizzled, register prefetch,
// FUSED Wp fp32->bf16 cast + head-permute in the B staging path)
__global__ __launch_bounds__(256, 3) void gemm_out(const uint16_t* __restrict__ A,   // O_concat bf16 [4096][1024]
                                                   const float* __restrict__ Wp,     // c_proj weight fp32 [1024][1024]
                                                   float* __restrict__ out) {        // [4096][1024] fp32
    __shared__ __align__(16) uint16_t As[128 * 64];
    __shared__ __align__(16) uint16_t Bs[64 * 64];

    int tid = threadIdx.x;
    int w = tid >> 6, lane = tid & 63;
    int qd = lane >> 4, ln = lane & 15;
    int lnx = ln & 7;
    int rowBase = blockIdx.y * 128;
    int colBase = blockIdx.x * 64;
    int mw = (w >> 1) * 64, nw = (w & 1) * 32;

    int srow = tid >> 3;
    int pchunk = tid & 7;
    int gchunk = pchunk ^ (srow & 7);

    const uint16_t* ga = A + (size_t)(rowBase + srow) * KDIM + gchunk * 8;
    // B logical: Wt[d][j], d = colBase+srow (+m*32), j = k-dim = h*64+v.
    // Wt[d][j] = Wp[h*65536 + d*64 + v]; 8 consecutive j (within one h) are contiguous in Wp.
    int j0 = gchunk * 8;
    int hh = j0 >> 6, vv = j0 & 63;
    const float* gbf = Wp + (size_t)hh * 65536 + (size_t)(colBase + srow) * 64 + vv;
    uint16_t* la = &As[srow * 64 + pchunk * 8];
    uint16_t* lb = &Bs[srow * 64 + pchunk * 8];

    short8 pa[4];
    float4 pbf[2][2];
#pragma unroll
    for (int m = 0; m < 4; m++)
        pa[m] = *(const short8*)(ga + (size_t)m * 32 * KDIM);
#pragma unroll
    for (int m = 0; m < 2; m++) {
        pbf[m][0] = *(const float4*)(gbf + (size_t)m * 32 * 64);
        pbf[m][1] = *(const float4*)(gbf + (size_t)m * 32 * 64 + 4);
    }

    f32x4 acc[4][2] = {};
    for (int s = 0; s < 16; s++) {
#pragma unroll
        for (int m = 0; m < 4; m++)
            *(short8*)(la + m * 32 * 64) = pa[m];
#pragma unroll
        for (int m = 0; m < 2; m++)
            *(short8*)(lb + m * 32 * 64) = cvt8(pbf[m][0], pbf[m][1]);
        __syncthreads();
        if (s < 15) {
            int k0 = (s + 1) * 64;           // k advance: j += 64 => h += 1 => Wp += 65536
#pragma unroll
            for (int m = 0; m < 4; m++)
                pa[m] = *(const short8*)(ga + k0 + (size_t)m * 32 * KDIM);
#pragma unroll
            for (int m = 0; m < 2; m++) {
                pbf[m][0] = *(const float4*)(gbf + (size_t)(s + 1) * 65536 + (size_t)m * 32 * 64);
                pbf[m][1] = *(const float4*)(gbf + (size_t)(s + 1) * 65536 + (size_t)m * 32 * 64 + 4);
            }
        }
#pragma unroll
        for (int ks = 0; ks < 2; ks++) {
            int p = (ks * 4 + qd) ^ lnx;
            short8 a[4], b[2];
#pragma unroll
            for (int i = 0; i < 4; i++)
                a[i] = *(const short8*)&As[(mw + i * 16 + ln) * 64 + p * 8];
#pragma unroll
            for (int j = 0; j < 2; j++)
                b[j] = *(const short8*)&Bs[(nw + j * 16 + ln) * 64 + p * 8];
#pragma unroll
            for (int i = 0; i < 4; i++)
#pragma unroll
                for (int j = 0; j < 2; j++)
                    acc[i][j] = __builtin_amdgcn_mfma_f32_16x16x32_bf16(a[i], b[j], acc[i][j], 0, 0, 0);
        }
        __syncthreads();
    }

#pragma unroll
    for (int i = 0; i < 4; i++)
#pragma unroll
        for (int j = 0; j < 2; j++)
#pragma unroll
            for (int r = 0; r < 4; r++) {
                int grow = rowBase + mw + i * 16 + qd * 4 + r;
                int gcol = colBase + nw + j * 16 + ln;
                out[(size_t)grow * 1024 + gcol] = acc[i][j][r];
            }
}

// ---------------------------------------------------------------- launch
extern "C" void kernel_launch(void* const* d_in, const int* in_sizes, int n_in,
                              void* d_out, int out_size, void* d_ws, size_t ws_size,
                              hipStream_t stream) {
    const float* x  = (const float*)d_in[0];
    const float* Wa = (const float*)d_in[1];
    const float* Wp = (const float*)d_in[2];
    float* out = (float*)d_out;

    uint16_t* ws   = (uint16_t*)d_ws;
    uint16_t* qkvb = ws;                         // Q,K: [bh][t][d] (Q pre-scaled by log2e); V: [bh][d][t]
    uint16_t* ob   = qkvb + (size_t)3 * 4194304; // 4096*1024

    gemm_qkv<<<dim3(24, 32), 256, 0, stream>>>(x, Wa, qkvb);
    attn<<<256, 512, 0, stream>>>(qkvb, ob);
    gemm_out<<<dim3(16, 32), 256, 0, stream>>>(ob, Wp, out);
}

// Round 7
// 164.891 us; speedup vs baseline: 1.1641x; 1.0827x over previous
//
#include <hip/hip_runtime.h>
#include <stdint.h>
#include <math.h>

// Problem constants
#define B_    2
#define T_    2048
#define C_    1024
#define H_    16
#define D_    64
#define MTOT  4096            // B*T
#define NQKV  3072            // 3*C
#define KDIM  1024            // C

#define LOG2E 1.4426950408889634f

typedef short short8 __attribute__((ext_vector_type(8)));   // 8 bf16 in 4 VGPRs
typedef float f32x4  __attribute__((ext_vector_type(4)));

__device__ __forceinline__ uint16_t f2b(float f) {
    union { float f; uint32_t u; } x; x.f = f;
    uint32_t u = x.u;
    return (uint16_t)((u + 0x7FFFu + ((u >> 16) & 1u)) >> 16);   // RNE
}
// fast pack of two floats -> two bf16 in one u32 (round-to-nearest, no tie-even)
__device__ __forceinline__ uint32_t packb2(float a, float b) {
    union { float f; uint32_t u; } x, y; x.f = a; y.f = b;
    return ((x.u + 0x8000u) >> 16) | ((y.u + 0x8000u) & 0xffff0000u);
}
__device__ __forceinline__ uint32_t packb2_rne(float a, float b) {
    return (uint32_t)f2b(a) | ((uint32_t)f2b(b) << 16);
}
__device__ __forceinline__ float fexp2(float x) {
#if __has_builtin(__builtin_amdgcn_exp2f)
    return __builtin_amdgcn_exp2f(x);
#else
    return exp2f(x);
#endif
}

// ---------------------------------------------------------------- casts (merged)
// One fp32 pass -> compact bf16 copies; the GEMMs re-read panels 24-32x, so the
// bf16 intermediates halve all L2->L1 re-read traffic (R6 lesson: fusing the cast
// into the GEMM doubles FETCH_SIZE and loses ~23us).
__global__ __launch_bounds__(256) void cast_all(const float* __restrict__ x,
                                                const float* __restrict__ wa,
                                                uint16_t* __restrict__ xb,
                                                uint16_t* __restrict__ wab,
                                                int n4x, int n4w) {
    int i = blockIdx.x * blockDim.x + threadIdx.x;
    const float* src; uint16_t* dst; int j;
    if (i < n4x) { src = x; dst = xb; j = i; }
    else { j = i - n4x; if (j >= n4w) return; src = wa; dst = wab; }
    float4 v = ((const float4*)src)[j];
    ushort4 o;
    o.x = f2b(v.x); o.y = f2b(v.y); o.z = f2b(v.z); o.w = f2b(v.w);
    ((ushort4*)dst)[j] = o;
}

// Wt[d][j=h*64+v] = Wp_flat[h*65536 + d*64 + v], bf16
__global__ __launch_bounds__(256) void cast_wp(const float* __restrict__ wp,
                                               uint16_t* __restrict__ wt) {
    int i = blockIdx.x * blockDim.x + threadIdx.x;   // over 1024*1024/4
    int j4 = (i & 255) * 4;
    int d  = i >> 8;
    int h = j4 >> 6, v = j4 & 63;
    float4 val = *(const float4*)(wp + h * 65536 + d * 64 + v);
    ushort4 o;
    o.x = f2b(val.x); o.y = f2b(val.y); o.z = f2b(val.z); o.w = f2b(val.w);
    *(ushort4*)(wt + d * 1024 + j4) = o;
}

// ---------------------------------------------------------------- GEMM1 (BK=64, swizzled LDS, 2-deep A prefetch)
// qkv = x @ Wa^T; scatter: Q (scaled by log2e), K -> [B][H][T][D]; V -> [B][H][D][T]
// Per-CU L2->L1 line-BW bound: deeper register prefetch (A 2 tiles ahead) keeps more
// lines in flight per wave. Even/odd named register sets keep indexing static (rule #20).
__global__ __launch_bounds__(256, 3) void gemm_qkv(const uint16_t* __restrict__ A,   // x bf16 [4096][1024]
                                                   const uint16_t* __restrict__ Bw,  // Wa bf16 [3072][1024]
                                                   uint16_t* __restrict__ qkvb) {
    __shared__ __align__(16) uint16_t As[128 * 64];   // swizzled: (r,k) at r*64 + ((k/8)^(r&7))*8 + k%8
    __shared__ __align__(16) uint16_t Bs[128 * 64];

    int tid = threadIdx.x;
    int w = tid >> 6, lane = tid & 63;
    int qd = lane >> 4, ln = lane & 15;
    int lnx = ln & 7;
    int rowBase = blockIdx.y * 128;
    int colBase = blockIdx.x * 128;
    int mw = (w >> 1) * 64, nw = (w & 1) * 64;

    int srow = tid >> 3;                 // 0..31
    int pchunk = tid & 7;                // physical chunk
    int gchunk = pchunk ^ (srow & 7);    // logical k-chunk for that slot

    const uint16_t* ga = A  + (size_t)(rowBase + srow) * KDIM + gchunk * 8;
    const uint16_t* gb = Bw + (size_t)(colBase + srow) * KDIM + gchunk * 8;
    uint16_t* la = &As[srow * 64 + pchunk * 8];
    uint16_t* lb = &Bs[srow * 64 + pchunk * 8];

    short8 paE[4], paO[4], pb[4];
#pragma unroll
    for (int m = 0; m < 4; m++) {
        paE[m] = *(const short8*)(ga + (size_t)m * 32 * KDIM);
        paO[m] = *(const short8*)(ga + 64 + (size_t)m * 32 * KDIM);
        pb[m]  = *(const short8*)(gb + (size_t)m * 32 * KDIM);
    }

    f32x4 acc[4][4] = {};

#define QSTEP(PAC, S)                                                            \
    {                                                                            \
        _Pragma("unroll")                                                        \
        for (int m = 0; m < 4; m++) {                                            \
            *(short8*)(la + m * 32 * 64) = PAC[m];                               \
            *(short8*)(lb + m * 32 * 64) = pb[m];                                \
        }                                                                        \
        __syncthreads();                                                         \
        if ((S) + 1 < 16) {                                                      \
            int kb_ = ((S) + 1) * 64;                                            \
            _Pragma("unroll")                                                    \
            for (int m = 0; m < 4; m++)                                          \
                pb[m] = *(const short8*)(gb + kb_ + (size_t)m * 32 * KDIM);      \
        }                                                                        \
        if ((S) + 2 < 16) {                                                      \
            int ka_ = ((S) + 2) * 64;                                            \
            _Pragma("unroll")                                                    \
            for (int m = 0; m < 4; m++)                                          \
                PAC[m] = *(const short8*)(ga + ka_ + (size_t)m * 32 * KDIM);     \
        }                                                                        \
        _Pragma("unroll")                                                        \
        for (int ks = 0; ks < 2; ks++) {                                         \
            int p = (ks * 4 + qd) ^ lnx;                                         \
            short8 a_[4], b_[4];                                                 \
            _Pragma("unroll")                                                    \
            for (int i = 0; i < 4; i++) {                                        \
                a_[i] = *(const short8*)&As[(mw + i * 16 + ln) * 64 + p * 8];    \
                b_[i] = *(const short8*)&Bs[(nw + i * 16 + ln) * 64 + p * 8];    \
            }                                                                    \
            _Pragma("unroll")                                                    \
            for (int i = 0; i < 4; i++)                                          \
                _Pragma("unroll")                                                \
                for (int j = 0; j < 4; j++)                                      \
                    acc[i][j] = __builtin_amdgcn_mfma_f32_16x16x32_bf16(a_[i], b_[j], acc[i][j], 0, 0, 0); \
        }                                                                        \
        __syncthreads();                                                         \
    }

    for (int sp = 0; sp < 8; sp++) {
        QSTEP(paE, 2 * sp);
        QSTEP(paO, 2 * sp + 1);
    }
#undef QSTEP

#pragma unroll
    for (int i = 0; i < 4; i++) {
#pragma unroll
        for (int j = 0; j < 4; j++) {
            int gcol = colBase + nw + j * 16 + ln;
            int which = gcol >> 10;
            int rem = gcol & 1023;
            int h = rem >> 6, d = rem & 63;
            if (which == 2) {
                // V^T: 4 consecutive t per thread -> one 8B packed store (t0 4-aligned)
                int t0 = rowBase + mw + i * 16 + qd * 4;
                int bb = t0 >> 11, t = t0 & 2047;
                uint2 pk2;
                pk2.x = packb2_rne(acc[i][j][0], acc[i][j][1]);
                pk2.y = packb2_rne(acc[i][j][2], acc[i][j][3]);
                *(uint2*)&qkvb[(size_t)2 * 4194304 + (((size_t)(bb * H_ + h) * D_) + d) * T_ + t] = pk2;
            } else {
                float sc = (which == 0) ? LOG2E : 1.0f;   // Q pre-scaled so attn uses exp2
#pragma unroll
                for (int r = 0; r < 4; r++) {
                    int grow = rowBase + mw + i * 16 + qd * 4 + r;
                    int bb = grow >> 11, t = grow & 2047;
                    uint16_t val = f2b(acc[i][j][r] * sc);
                    qkvb[(size_t)which * 4194304 + (((size_t)(bb * H_ + h) * T_) + t) * D_ + d] = val;
                }
            }
        }
    }
}

// ---------------------------------------------------------------- attention
// Per-CU-unique-line bound => share K/V tiles across waves via LDS.
// Block = 8 waves (512 thr), handles q-groups j and 15-j (128 q-rows each) in ONE
// fused kt loop (nt = 32-2j staging iterations, 34 strip-iterations — balanced).
// Wave w owns q-rows [qg*128+w*16, +16) exclusively: no split-K, no combine.
// K/V tiles staged once per block per kt (swizzled, reg-prefetch, dbuf, 1 barrier/kt).
// S^T = K Q^T; p = exp2(s) (Q pre-scaled by log2e); P^T via per-wave LDS; O^T = Vt P^T.

#define STRIP(QS, BQ, OT, LSUM)                                              \
    if (kt * 64 <= (QS) + 15) {                                              \
        bool needm = (kt * 64 + 63 > (QS));                                  \
        f32x4 stt[4];                                                        \
        __builtin_amdgcn_s_setprio(1);                                       \
        _Pragma("unroll")                                                    \
        for (int it = 0; it < 4; it++) {                                     \
            f32x4 z = {};                                                    \
            z = __builtin_amdgcn_mfma_f32_16x16x32_bf16(ak[it][0], (BQ)[0], z, 0, 0, 0); \
            z = __builtin_amdgcn_mfma_f32_16x16x32_bf16(ak[it][1], (BQ)[1], z, 0, 0, 0); \
            stt[it] = z;                                                     \
        }                                                                    \
        __builtin_amdgcn_s_setprio(0);                                       \
        if (needm) {                                                         \
            _Pragma("unroll")                                                \
            for (int it = 0; it < 4; it++)                                   \
                _Pragma("unroll")                                            \
                for (int r = 0; r < 4; r++) {                                \
                    int t = kt * 64 + it * 16 + qd * 4 + r;                  \
                    if (t > (QS) + ln) stt[it][r] = -1.0e30f;                \
                }                                                            \
        }                                                                    \
        _Pragma("unroll")                                                    \
        for (int it = 0; it < 4; it++) {                                     \
            float p0 = fexp2(stt[it][0]);                                    \
            float p1 = fexp2(stt[it][1]);                                    \
            float p2 = fexp2(stt[it][2]);                                    \
            float p3 = fexp2(stt[it][3]);                                    \
            (LSUM) += (p0 + p1) + (p2 + p3);                                 \
            uint2 pk2;                                                       \
            pk2.x = packb2(p0, p1);                                          \
            pk2.y = packb2(p2, p3);                                          \
            *(uint2*)&Pl[w][ln][it * 16 + qd * 4] = pk2;                     \
        }                                                                    \
        short8 bp0 = *(const short8*)&Pl[w][ln][qd * 8];                     \
        short8 bp1 = *(const short8*)&Pl[w][ln][32 + qd * 8];                \
        __builtin_amdgcn_s_setprio(1);                                       \
        _Pragma("unroll")                                                    \
        for (int id = 0; id < 4; id++) {                                     \
            (OT)[id] = __builtin_amdgcn_mfma_f32_16x16x32_bf16(av[id][0], bp0, (OT)[id], 0, 0, 0); \
            (OT)[id] = __builtin_amdgcn_mfma_f32_16x16x32_bf16(av[id][1], bp1, (OT)[id], 0, 0, 0); \
        }                                                                    \
        __builtin_amdgcn_s_setprio(0);                                       \
    }

#define EPI(QS, OT, LSUM)                                                    \
    {                                                                        \
        float ssum = (LSUM);                                                 \
        ssum += __shfl_xor(ssum, 16);                                        \
        ssum += __shfl_xor(ssum, 32);                                        \
        float rl = 1.0f / ssum;                                              \
        int q = (QS) + ln;                                                   \
        _Pragma("unroll")                                                    \
        for (int id = 0; id < 4; id++) {                                     \
            float v0 = (OT)[id][0] * rl;                                     \
            float v1 = (OT)[id][1] * rl;                                     \
            float v2 = (OT)[id][2] * rl;                                     \
            float v3 = (OT)[id][3] * rl;                                     \
            uint2 pk2;                                                       \
            pk2.x = packb2_rne(v0, v1);                                      \
            pk2.y = packb2_rne(v2, v3);                                      \
            *(uint2*)&oc[(size_t)(b * T_ + q) * C_ + h * 64 + id * 16 + qd * 4] = pk2; \
        }                                                                    \
    }

__global__ __launch_bounds__(512, 2) void attn(const uint16_t* __restrict__ qkvb,
                                               uint16_t* __restrict__ oc) {         // O_concat bf16 [4096][1024]
    __shared__ __align__(16) uint16_t Ks[2][64 * 64];   // swizzled: (t, chunk c) at t*64 + (c^(t&7))*8
    __shared__ __align__(16) uint16_t Vs[2][64 * 64];   // swizzled: (d, chunk c) likewise
    __shared__ __align__(16) uint16_t Pl[8][16][72];    // per-wave P^T strip [q16][t64+pad]

    int tid = threadIdx.x;
    int w = tid >> 6, lane = tid & 63;
    int qd = lane >> 4, ln = lane & 15;
    int lnx = ln & 7;
    int bid = blockIdx.x;
    int j = bid >> 5;                  // 0..7 pair index
    int bh = bid & 31;                 // bid%8 == bh%8 → bh→XCD L2 affinity
    int b = bh >> 4, h = bh & 15;

    const uint16_t* Q0 = qkvb + (size_t)bh * T_ * D_;
    const uint16_t* K  = Q0 + 4194304;
    const uint16_t* Vt = qkvb + (size_t)2 * 4194304 + (size_t)bh * D_ * T_;   // [64 d][2048 t]

    int qsA = j * 128 + w * 16;        // light q-group
    int qsB = (15 - j) * 128 + w * 16; // heavy q-group
    int nt  = 32 - 2 * j;              // k-tiles needed by the heavy group

    // persistent Q fragments (B-operand, n=q16, k=d)
    short8 bqA[2], bqB[2];
#pragma unroll
    for (int ks = 0; ks < 2; ks++) {
        bqA[ks] = *(const short8*)(Q0 + (size_t)(qsA + ln) * D_ + ks * 32 + qd * 8);
        bqB[ks] = *(const short8*)(Q0 + (size_t)(qsB + ln) * D_ + ks * 32 + qd * 8);
    }

    // staging: 512 threads cover 64 rows x 8 chunks of 16B, chunk XOR-swizzled
    int srow = tid >> 3;               // 0..63
    int pch = tid & 7;
    int gch = pch ^ (srow & 7);
    const uint16_t* gk = K  + (size_t)srow * D_ + gch * 8;   // K row = kt*64+srow
    const uint16_t* gv = Vt + (size_t)srow * T_ + gch * 8;   // V^T row d = srow, col = kt*64+..
    int lofs = srow * 64 + pch * 8;

    short8 pk = *(const short8*)gk;    // tile kt=0 prefetch
    short8 pv = *(const short8*)gv;

    f32x4 otA[4] = {}, otB[4] = {};    // O^T [d-tile id][q16], per strip
    float lA = 0.f, lB = 0.f;

    int c = 0;
    for (int kt = 0; kt < nt; kt++) {
        *(short8*)&Ks[c][lofs] = pk;
        *(short8*)&Vs[c][lofs] = pv;
        __syncthreads();
        if (kt + 1 < nt) {
            pk = *(const short8*)(gk + (size_t)(kt + 1) * 64 * D_);
            pv = *(const short8*)(gv + (size_t)(kt + 1) * 64);
        }
        // shared K/V fragments for both strips (A-operands)
        short8 ak[4][2], av[4][2];
#pragma unroll
        for (int ks = 0; ks < 2; ks++) {
            int p8 = ((ks * 4 + qd) ^ lnx) * 8;
#pragma unroll
            for (int it = 0; it < 4; it++) {
                ak[it][ks] = *(const short8*)&Ks[c][(it * 16 + ln) * 64 + p8];
                av[it][ks] = *(const short8*)&Vs[c][(it * 16 + ln) * 64 + p8];
            }
        }
        STRIP(qsA, bqA, otA, lA);
        STRIP(qsB, bqB, otB, lB);
        c ^= 1;
    }

    EPI(qsA, otA, lA);
    EPI(qsB, otB, lB);
}

// ---------------------------------------------------------------- GEMM2 (tile 128x64, BK=64, swizzled, 2-deep A prefetch)
__global__ __launch_bounds__(256, 3) void gemm_out(const uint16_t* __restrict__ A,   // O_concat bf16 [4096][1024]
                                                   const uint16_t* __restrict__ Bw,  // Wt bf16 [1024][1024]
                                                   float* __restrict__ out) {        // [4096][1024] fp32
    __shared__ __align__(16) uint16_t As[128 * 64];
    __shared__ __align__(16) uint16_t Bs[64 * 64];

    int tid = threadIdx.x;
    int w = tid >> 6, lane = tid & 63;
    int qd = lane >> 4, ln = lane & 15;
    int lnx = ln & 7;
    int rowBase = blockIdx.y * 128;
    int colBase = blockIdx.x * 64;
    int mw = (w >> 1) * 64, nw = (w & 1) * 32;

    int srow = tid >> 3;
    int pchunk = tid & 7;
    int gchunk = pchunk ^ (srow & 7);

    const uint16_t* ga = A  + (size_t)(rowBase + srow) * KDIM + gchunk * 8;
    const uint16_t* gb = Bw + (size_t)(colBase + srow) * KDIM + gchunk * 8;
    uint16_t* la = &As[srow * 64 + pchunk * 8];
    uint16_t* lb = &Bs[srow * 64 + pchunk * 8];

    short8 paE[4], paO[4], pb[2];
#pragma unroll
    for (int m = 0; m < 4; m++) {
        paE[m] = *(const short8*)(ga + (size_t)m * 32 * KDIM);
        paO[m] = *(const short8*)(ga + 64 + (size_t)m * 32 * KDIM);
    }
#pragma unroll
    for (int m = 0; m < 2; m++)
        pb[m] = *(const short8*)(gb + (size_t)m * 32 * KDIM);

    f32x4 acc[4][2] = {};

#define OSTEP(PAC, S)                                                            \
    {                                                                            \
        _Pragma("unroll")                                                        \
        for (int m = 0; m < 4; m++)                                              \
            *(short8*)(la + m * 32 * 64) = PAC[m];                               \
        _Pragma("unroll")                                                        \
        for (int m = 0; m < 2; m++)                                              \
            *(short8*)(lb + m * 32 * 64) = pb[m];                                \
        __syncthreads();                                                         \
        if ((S) + 1 < 16) {                                                      \
            int kb_ = ((S) + 1) * 64;                                            \
            _Pragma("unroll")                                                    \
            for (int m = 0; m < 2; m++)                                          \
                pb[m] = *(const short8*)(gb + kb_ + (size_t)m * 32 * KDIM);      \
        }                                                                        \
        if ((S) + 2 < 16) {                                                      \
            int ka_ = ((S) + 2) * 64;                                            \
            _Pragma("unroll")                                                    \
            for (int m = 0; m < 4; m++)                                          \
                PAC[m] = *(const short8*)(ga + ka_ + (size_t)m * 32 * KDIM);     \
        }                                                                        \
        _Pragma("unroll")                                                        \
        for (int ks = 0; ks < 2; ks++) {                                         \
            int p = (ks * 4 + qd) ^ lnx;                                         \
            short8 a_[4], b_[2];                                                 \
            _Pragma("unroll")                                                    \
            for (int i = 0; i < 4; i++)                                          \
                a_[i] = *(const short8*)&As[(mw + i * 16 + ln) * 64 + p * 8];    \
            _Pragma("unroll")                                                    \
            for (int j = 0; j < 2; j++)                                          \
                b_[j] = *(const short8*)&Bs[(nw + j * 16 + ln) * 64 + p * 8];    \
            _Pragma("unroll")                                                    \
            for (int i = 0; i < 4; i++)                                          \
                _Pragma("unroll")                                                \
                for (int j = 0; j < 2; j++)                                      \
                    acc[i][j] = __builtin_amdgcn_mfma_f32_16x16x32_bf16(a_[i], b_[j], acc[i][j], 0, 0, 0); \
        }                                                                        \
        __syncthreads();                                                         \
    }

    for (int sp = 0; sp < 8; sp++) {
        OSTEP(paE, 2 * sp);
        OSTEP(paO, 2 * sp + 1);
    }
#undef OSTEP

#pragma unroll
    for (int i = 0; i < 4; i++)
#pragma unroll
        for (int j = 0; j < 2; j++)
#pragma unroll
            for (int r = 0; r < 4; r++) {
                int grow = rowBase + mw + i * 16 + qd * 4 + r;
                int gcol = colBase + nw + j * 16 + ln;
                out[(size_t)grow * 1024 + gcol] = acc[i][j][r];
            }
}

// ---------------------------------------------------------------- launch
extern "C" void kernel_launch(void* const* d_in, const int* in_sizes, int n_in,
                              void* d_out, int out_size, void* d_ws, size_t ws_size,
                              hipStream_t stream) {
    const float* x  = (const float*)d_in[0];
    const float* Wa = (const float*)d_in[1];
    const float* Wp = (const float*)d_in[2];
    float* out = (float*)d_out;

    uint16_t* ws   = (uint16_t*)d_ws;
    uint16_t* xb   = ws;                       // 4096*1024
    uint16_t* Wab  = xb + 4194304;             // 3072*1024
    uint16_t* Wtb  = Wab + 3145728;            // 1024*1024
    uint16_t* qkvb = Wtb + 1048576;            // Q,K: [bh][t][d] (Q pre-scaled by log2e); V: [bh][d][t]
    uint16_t* ob   = qkvb + (size_t)3 * 4194304; // 4096*1024

    cast_all<<<7168, 256, 0, stream>>>(x, Wa, xb, Wab, 4194304 / 4, 3145728 / 4);
    cast_wp<<<1024, 256, 0, stream>>>(Wp, Wtb);
    gemm_qkv<<<dim3(24, 32), 256, 0, stream>>>(xb, Wab, qkvb);
    attn<<<256, 512, 0, stream>>>(qkvb, ob);
    gemm_out<<<dim3(16, 32), 256, 0, stream>>>(ob, Wtb, out);
}